// Round 14
// baseline (1408.714 us; speedup 1.0000x reference)
//
#include <hip/hip_runtime.h>
#include <hip/hip_bf16.h>
#include <math.h>

#define NND 100000   // nodes
#define EE  200000   // edges
#define LL  3        // layers
#define DD  300      // node dim
#define HH  150      // per-direction message dim

#define MPAD 100096  // 782*128
#define KP   320     // K padded (multiple of 32)
#define NPJ  640     // proj N padded
#define NUP  384     // update N padded
#define NTK  (KP / 32)

#define NB   49          // scan blocks (2048 elems each)
#define SCN  (NB * 2048) // 100352 >= MPAD+1

// P column layout (all 8B-aligned region starts, pads zero):
//  Br @ 0..149 | Bc @ 152..301 | Ar @ 304..453 | Ac @ 456..605
#define P_BR 0
#define P_BC 152
#define P_AR 304
#define P_AC 456
// RC column layout: r @ 0..149, pad, c @ 160..309, pad
#define RC_R 0
#define RC_C 160

typedef __attribute__((ext_vector_type(8))) short bf16x8;
typedef __attribute__((ext_vector_type(4))) short bf16x4;
typedef __attribute__((ext_vector_type(4))) float f32x4;

__device__ __forceinline__ float gelu_exact(float z) {
    return 0.5f * z * (1.0f + erff(z * 0.7071067811865475f));
}
__device__ __forceinline__ unsigned short f2bf(float f) {
    union { float fv; unsigned u; } v; v.fv = f;
    unsigned r = v.u + 0x7fff + ((v.u >> 16) & 1);   // RNE (finite inputs)
    return (unsigned short)(r >> 16);
}
__device__ __forceinline__ float bf2f(unsigned short b) {
    union { unsigned u; float fv; } v; v.u = ((unsigned)b) << 16;
    return v.fv;
}

// ---------------- weight packing ----------------
__global__ __launch_bounds__(256) void pack_w(
    const float* __restrict__ Wr, const float* __restrict__ Wc,
    const float* __restrict__ Wa,
    unsigned short* __restrict__ Bt, unsigned short* __restrict__ Wat)
{
    int i = blockIdx.x * 256 + threadIdx.x;
    const int btTotal = LL * NPJ * KP;
    if (i < btTotal) {
        int l = i / (NPJ * KP);
        int rem = i % (NPJ * KP);
        int n = rem / KP;
        int k = rem % KP;
        float v = 0.f;
        if (k < DD) {
            const float* W = nullptr; int krow = k, j = -1;
            if (n >= P_BR && n < P_BR + 150)      { W = Wr; krow = 300 + k; j = n - P_BR; }
            else if (n >= P_BC && n < P_BC + 150) { W = Wc; krow = 300 + k; j = n - P_BC; }
            else if (n >= P_AR && n < P_AR + 150) { W = Wr; krow = k;       j = n - P_AR; }
            else if (n >= P_AC && n < P_AC + 150) { W = Wc; krow = k;       j = n - P_AC; }
            if (j >= 0)
                v = W[(size_t)l * 600 * 150 + (size_t)krow * 150 + j];
        }
        Bt[i] = f2bf(v);
    } else {
        int i2 = i - btTotal;
        if (i2 < NUP * KP) {
            int n = i2 / KP, k = i2 % KP;
            int kk = -1;
            if (k < 150)                 kk = k;          // r rows of Wa
            else if (k >= 160 && k < 310) kk = k - 10;    // c rows of Wa
            float v = (n < DD && kk >= 0) ? Wa[(size_t)kk * DD + n] : 0.f;
            Wat[i2] = f2bf(v);
        }
    }
}

// vbf[MPAD][KP] = bf16(x), zero pads
__global__ __launch_bounds__(256) void init_vbf(
    const float* __restrict__ x, unsigned short* __restrict__ vbf)
{
    int idx = blockIdx.x * 256 + threadIdx.x;       // chunk of 8
    int row = idx / (KP / 8);
    int gk  = (idx % (KP / 8)) * 8;
    if (row >= MPAD) return;
    unsigned short tmp[8];
    if (row < NND && gk < DD) {
        if (gk + 8 <= DD) {
            const float4* p = (const float4*)(x + (size_t)row * DD + gk);
            float4 f0 = p[0], f1 = p[1];
            tmp[0] = f2bf(f0.x); tmp[1] = f2bf(f0.y);
            tmp[2] = f2bf(f0.z); tmp[3] = f2bf(f0.w);
            tmp[4] = f2bf(f1.x); tmp[5] = f2bf(f1.y);
            tmp[6] = f2bf(f1.z); tmp[7] = f2bf(f1.w);
        } else {
            #pragma unroll
            for (int j = 0; j < 8; ++j)
                tmp[j] = (gk + j < DD) ? f2bf(x[(size_t)row * DD + gk + j]) : 0;
        }
    } else {
        #pragma unroll
        for (int j = 0; j < 8; ++j) tmp[j] = 0;
    }
    *((bf16x8*)&vbf[(size_t)row * KP + gk]) = *((bf16x8*)tmp);
}

// ---------------- CSR build ----------------
__global__ __launch_bounds__(256) void hist_deg(
    const int* __restrict__ src, const int* __restrict__ dst,
    int* __restrict__ deg)
{
    int e = blockIdx.x * 256 + threadIdx.x;
    if (e >= EE) return;
    atomicAdd(&deg[dst[e]], 1);
    atomicAdd(&deg[SCN + src[e]], 1);
}

__global__ __launch_bounds__(256) void scanA(
    const int* __restrict__ deg, int* __restrict__ off, int* __restrict__ bsum)
{
    __shared__ int ls[256];
    const int t = threadIdx.x, row = blockIdx.y;
    const int base = blockIdx.x * 2048 + t * 8;
    const int* dg = deg + (size_t)row * SCN + base;
    int v[8];
    #pragma unroll
    for (int j = 0; j < 8; ++j) v[j] = dg[j];
    int tot = 0;
    #pragma unroll
    for (int j = 0; j < 8; ++j) tot += v[j];
    ls[t] = tot;
    __syncthreads();
    #pragma unroll
    for (int d = 1; d < 256; d <<= 1) {
        int tv = (t >= d) ? ls[t - d] : 0;
        __syncthreads();
        ls[t] += tv;
        __syncthreads();
    }
    int run = ls[t] - tot;
    int* op = off + (size_t)row * SCN + base;
    #pragma unroll
    for (int j = 0; j < 8; ++j) { op[j] = run; run += v[j]; }
    if (t == 255) bsum[row * 64 + blockIdx.x] = ls[255];
}

__global__ __launch_bounds__(256) void scanB(int* __restrict__ bsum)
{
    if (threadIdx.x < 2) {
        int row = threadIdx.x, c = 0;
        for (int i = 0; i < NB; ++i) {
            int tv = bsum[row * 64 + i];
            bsum[row * 64 + i] = c;
            c += tv;
        }
    }
}

__global__ __launch_bounds__(256) void scanC(
    int* __restrict__ off, const int* __restrict__ bsum, int* __restrict__ cur)
{
    const int t = threadIdx.x, row = blockIdx.y;
    const int base = blockIdx.x * 2048 + t * 8;
    const int add = bsum[row * 64 + blockIdx.x];
    int* op = off + (size_t)row * SCN + base;
    int* cp = cur + (size_t)row * SCN + base;
    #pragma unroll
    for (int j = 0; j < 8; ++j) {
        int v = op[j] + add;
        op[j] = v;
        cp[j] = v;
    }
}

__global__ __launch_bounds__(256) void fill_adj(
    const int* __restrict__ src, const int* __restrict__ dst,
    int* __restrict__ cur, int* __restrict__ adj)
{
    int e = blockIdx.x * 256 + threadIdx.x;
    if (e >= EE) return;
    int s = src[e], d = dst[e];
    int pd = atomicAdd(&cur[d], 1);
    adj[pd] = s;
    int ps = atomicAdd(&cur[SCN + s], 1);
    adj[EE + ps] = d;
}

// ---------------- aggregation (no atomics, vectorized aligned gathers) ------
__global__ __launch_bounds__(256) void aggregate(
    const int* __restrict__ off, const int* __restrict__ adj,
    const unsigned short* __restrict__ P,
    const float* __restrict__ br, const float* __restrict__ bc,
    unsigned short* __restrict__ RC)
{
    const int n    = blockIdx.x * 4 + (threadIdx.x >> 6);
    const int dir  = blockIdx.y;
    const int lane = threadIdx.x & 63;
    const int c    = lane * 4;             // col base within 150-wide region

    if (lane < 10)
        RC[(size_t)n * KP + (dir ? 310 : 150) + lane] = 0;
    if (c >= 152) return;

    const int* offp = off + (size_t)dir * SCN;
    const int* adjp = adj + (size_t)dir * EE;
    const float* bias = dir ? bc : br;
    const unsigned short* own = P + (size_t)n * NPJ + (dir ? P_AC : P_AR);
    const int poff = dir ? P_BC : P_BR;

    const bool g0 = (c + 0) < 150, g1 = (c + 1) < 150;
    const bool g2 = (c + 2) < 150, g3 = (c + 3) < 150;

    bf16x4 ow = *((const bf16x4*)&own[c]);
    float o0 = bf2f((unsigned short)ow[0]) + (g0 ? bias[c + 0] : 0.f);
    float o1 = bf2f((unsigned short)ow[1]) + (g1 ? bias[c + 1] : 0.f);
    float o2 = bf2f((unsigned short)ow[2]) + (g2 ? bias[c + 2] : 0.f);
    float o3 = bf2f((unsigned short)ow[3]) + (g3 ? bias[c + 3] : 0.f);

    float s0 = 0.f, s1 = 0.f, s2 = 0.f, s3 = 0.f;
    int beg = offp[n], end = offp[n + 1];
    if (beg < end) {
        int a = adjp[beg];
        for (int i = beg; i < end; ++i) {
            int anext = (i + 1 < end) ? adjp[i + 1] : 0;
            const unsigned short* pp = P + (size_t)a * NPJ + poff;
            bf16x4 pv = *((const bf16x4*)&pp[c]);
            s0 += gelu_exact(o0 + bf2f((unsigned short)pv[0]));
            s1 += gelu_exact(o1 + bf2f((unsigned short)pv[1]));
            s2 += gelu_exact(o2 + bf2f((unsigned short)pv[2]));
            s3 += gelu_exact(o3 + bf2f((unsigned short)pv[3]));
            a = anext;
        }
    }
    unsigned short* outrow = RC + (size_t)n * KP + (dir ? RC_C : RC_R);
    if (c + 4 <= 150) {
        bf16x4 o;
        o[0] = (short)f2bf(s0); o[1] = (short)f2bf(s1);
        o[2] = (short)f2bf(s2); o[3] = (short)f2bf(s3);
        *((bf16x4*)&outrow[c]) = o;
    } else {
        if (g0) outrow[c + 0] = f2bf(s0);
        if (g1) outrow[c + 1] = f2bf(s1);
    }
}

// -------- barrier-free wave GEMM: 32x64 per wave, all-register pipeline ------
// No LDS, no barriers in the K-loop. A 3-steps-ahead (4-slot reg ring),
// B 1-step-ahead (2-slot ring), asm loads (deterministic vmcnt counting),
// counted s_waitcnt vmcnt(N) + sched_barrier(0) per step (rule 18).
#define LDG(dst, voff, base, OFF) \
    asm volatile("global_load_dwordx4 %0, %1, %2 offset:" OFF \
                 : "=v"(dst) : "v"(voff), "s"(base) : "memory")

#define LOADA(S, OFF) do { \
    LDG(ar[S][0], va0, Ab, OFF); LDG(ar[S][1], va1, Ab, OFF); } while (0)

#define LOADB(S, OFF) do { \
    LDG(brg[S][0], vb0, Bt, OFF); LDG(brg[S][1], vb1, Bt, OFF); \
    LDG(brg[S][2], vb2, Bt, OFF); LDG(brg[S][3], vb3, Bt, OFF); } while (0)

#define WAITV(N) do { \
    asm volatile("s_waitcnt vmcnt(" #N ")" ::: "memory"); \
    __builtin_amdgcn_sched_barrier(0); } while (0)

#define MFMA8(TA, TB) do { \
    _Pragma("unroll") \
    for (int g_ = 0; g_ < 2; ++g_) { \
        _Pragma("unroll") \
        for (int nj_ = 0; nj_ < 4; ++nj_) \
            acc[g_][nj_] = __builtin_amdgcn_mfma_f32_16x16x32_bf16( \
                ar[TA][g_], brg[TB][nj_], acc[g_][nj_], 0, 0, 0); \
    } } while (0)

// MODE 0: P[row*NPJ+col] = bf16(acc)
// MODE 1: nv = vbf_old + gelu(acc + bias[col]); last? out=fp32(nv) : vbf=bf16(nv)
template<int MODE>
__global__ __launch_bounds__(256, 4) void gemm_wave(
    const unsigned short* __restrict__ Ab,
    const unsigned short* __restrict__ Bt,
    unsigned short* __restrict__ P,
    float* __restrict__ outv, unsigned short* __restrict__ vbf,
    const float* __restrict__ bias, int last)
{
    __shared__ char smem[4 * 4608];    // per-wave private bounce (no barriers)

    const int tid  = threadIdx.x;
    const int lane = tid & 63;
    const int wid  = tid >> 6;

    // bijective XCD swizzle (m204)
    const int gx   = gridDim.x;
    const int nwg  = gx * gridDim.y;
    const int flat = blockIdx.y * gx + blockIdx.x;
    const int q = nwg >> 3, r = nwg & 7;
    const int xcd = flat & 7, off = flat >> 3;
    const int lid = (xcd < r ? xcd * (q + 1) : r * (q + 1) + (xcd - r) * q) + off;
    const int brow = (lid / gx) * 128;
    const int bcol = (lid % gx) * 64;
    const int wrow = brow + wid * 32;

    // byte voffsets (SGPR base + 32b voffset addressing)
    const unsigned va0 = (unsigned)(wrow + (lane & 15)) * (KP * 2) + (lane >> 4) * 16;
    const unsigned va1 = va0 + 16 * KP * 2;
    const unsigned vb0 = (unsigned)(bcol + (lane & 15)) * (KP * 2) + (lane >> 4) * 16;
    const unsigned vb1 = vb0 + 16 * KP * 2;
    const unsigned vb2 = vb0 + 32 * KP * 2;
    const unsigned vb3 = vb0 + 48 * KP * 2;

    bf16x8 ar[4][2];    // A ring: 4 slots x 2 frags
    bf16x8 brg[2][4];   // B ring: 2 slots x 4 frags
    f32x4 acc[2][4];
    #pragma unroll
    for (int i = 0; i < 2; ++i)
        #pragma unroll
        for (int j = 0; j < 4; ++j)
            #pragma unroll
            for (int rr = 0; rr < 4; ++rr) acc[i][j][rr] = 0.f;

    // prologue: A(0..2), B(0)
    LOADA(0, "0"); LOADA(1, "64"); LOADA(2, "128"); LOADB(0, "0");
    // steady: per step issue B(t+1), A(t+3); wait (queue hand-simulated)
    LOADB(1, "64");  LOADA(3, "192"); WAITV(6); MFMA8(0, 0);   // t=0
    LOADB(0, "128"); LOADA(0, "256"); WAITV(8); MFMA8(1, 1);   // t=1
    LOADB(1, "192"); LOADA(1, "320"); WAITV(8); MFMA8(2, 0);   // t=2
    LOADB(0, "256"); LOADA(2, "384"); WAITV(8); MFMA8(3, 1);   // t=3
    LOADB(1, "320"); LOADA(3, "448"); WAITV(8); MFMA8(0, 0);   // t=4
    LOADB(0, "384"); LOADA(0, "512"); WAITV(8); MFMA8(1, 1);   // t=5
    LOADB(1, "448"); LOADA(1, "576"); WAITV(8); MFMA8(2, 0);   // t=6
    LOADB(0, "512");                  WAITV(6); MFMA8(3, 1);   // t=7
    LOADB(1, "576");                  WAITV(4); MFMA8(0, 0);   // t=8
                                      WAITV(0); MFMA8(1, 1);   // t=9

    // ---- wave-private epilogue (no barriers; compiler orders LDS ops) ----
    if (MODE == 0) {
        unsigned short* sb = (unsigned short*)(smem + wid * 4608);  // [32][72]
        #pragma unroll
        for (int g = 0; g < 2; ++g)
            #pragma unroll
            for (int nj = 0; nj < 4; ++nj)
                #pragma unroll
                for (int rr = 0; rr < 4; ++rr) {
                    int row = g * 16 + ((lane >> 4) << 2) + rr;
                    sb[row * 72 + nj * 16 + (lane & 15)] = f2bf(acc[g][nj][rr]);
                }
        #pragma unroll
        for (int i = 0; i < 4; ++i) {
            int row = i * 8 + (lane >> 3);
            bf16x8 v = *((const bf16x8*)&sb[row * 72 + (lane & 7) * 8]);
            *((bf16x8*)&P[(size_t)(wrow + row) * NPJ + bcol + (lane & 7) * 8]) = v;
        }
    } else {
        float* fb = (float*)(smem + wid * 4608);                    // [16][68]
        const int gc = bcol + (lane & 15) * 4;
        #pragma unroll
        for (int h = 0; h < 2; ++h) {
            #pragma unroll
            for (int nj = 0; nj < 4; ++nj)
                #pragma unroll
                for (int rr = 0; rr < 4; ++rr) {
                    int r16 = ((lane >> 4) << 2) + rr;
                    fb[r16 * 68 + nj * 16 + (lane & 15)] = acc[h][nj][rr];
                }
            #pragma unroll
            for (int i = 0; i < 4; ++i) {
                int r16 = i * 4 + (lane >> 4);
                int grow = wrow + h * 16 + r16;
                float4 vv = *((const float4*)&fb[r16 * 68 + (lane & 15) * 4]);
                if (grow < NND && gc + 3 < DD) {
                    float4 bv = *((const float4*)&bias[gc]);
                    bf16x4 old = *((const bf16x4*)&vbf[(size_t)grow * KP + gc]);
                    float4 nv;
                    nv.x = bf2f((unsigned short)old[0]) + gelu_exact(vv.x + bv.x);
                    nv.y = bf2f((unsigned short)old[1]) + gelu_exact(vv.y + bv.y);
                    nv.z = bf2f((unsigned short)old[2]) + gelu_exact(vv.z + bv.z);
                    nv.w = bf2f((unsigned short)old[3]) + gelu_exact(vv.w + bv.w);
                    if (last) {
                        *((float4*)&outv[(size_t)grow * DD + gc]) = nv;
                    } else {
                        bf16x4 o;
                        o[0] = (short)f2bf(nv.x); o[1] = (short)f2bf(nv.y);
                        o[2] = (short)f2bf(nv.z); o[3] = (short)f2bf(nv.w);
                        *((bf16x4*)&vbf[(size_t)grow * KP + gc]) = o;
                    }
                }
            }
        }
    }
}

extern "C" void kernel_launch(void* const* d_in, const int* in_sizes, int n_in,
                              void* d_out, int out_size, void* d_ws, size_t ws_size,
                              hipStream_t stream) {
    const float* x  = (const float*)d_in[0];
    const int*   ei = (const int*)  d_in[1];
    const float* Wr = (const float*)d_in[2];
    const float* br = (const float*)d_in[3];
    const float* Wc = (const float*)d_in[4];
    const float* bc = (const float*)d_in[5];
    const float* Wa = (const float*)d_in[6];
    const float* ba = (const float*)d_in[7];
    float* out = (float*)d_out;

    const size_t P_elems   = (size_t)MPAD * NPJ;   // bf16
    const size_t RC_elems  = (size_t)MPAD * KP;    // bf16
    const size_t V_elems   = (size_t)MPAD * KP;    // bf16
    const size_t Bt_elems  = (size_t)LL * NPJ * KP;
    const size_t Wat_elems = (size_t)NUP * KP;

    unsigned short* P   = (unsigned short*)d_ws;
    unsigned short* RC  = P + P_elems;
    unsigned short* vbf = RC + RC_elems;
    unsigned short* Bt  = vbf + V_elems;
    unsigned short* Wat = Bt + Bt_elems;
    int* deg  = (int*)(Wat + Wat_elems);
    int* off  = deg + 2 * SCN;
    int* curp = off + 2 * SCN;
    int* adj  = curp + 2 * SCN;
    int* bsum = adj + 2 * EE;
    const size_t need = (char*)(bsum + 128) - (char*)d_ws;
    if (ws_size < need) return;  // visible fail (output stays poisoned)

    pack_w<<<2880, 256, 0, stream>>>(Wr, Wc, Wa, Bt, Wat);
    init_vbf<<<(int)((V_elems / 8 + 255) / 256), 256, 0, stream>>>(x, vbf);

    const int* src = ei;
    const int* dst = ei + EE;

    hipMemsetAsync(deg, 0, 2 * SCN * sizeof(int), stream);
    hist_deg<<<(EE + 255) / 256, 256, 0, stream>>>(src, dst, deg);
    scanA<<<dim3(NB, 2), 256, 0, stream>>>(deg, off, bsum);
    scanB<<<1, 256, 0, stream>>>(bsum);
    scanC<<<dim3(NB, 2), 256, 0, stream>>>(off, bsum, curp);
    fill_adj<<<(EE + 255) / 256, 256, 0, stream>>>(src, dst, curp, adj);

    dim3 gproj(NPJ / 64, MPAD / 128);   // (10, 782)
    dim3 gupd (5,        MPAD / 128);   // cols 0..319 cover DD=300
    dim3 gagg (MPAD / 4, 2);

    for (int l = 0; l < LL; ++l) {
        gemm_wave<0><<<gproj, 256, 0, stream>>>(
            vbf, Bt + (size_t)l * NPJ * KP, P, nullptr, nullptr, nullptr, 0);
        aggregate<<<gagg, 256, 0, stream>>>(
            off, adj, P, br + (size_t)l * HH, bc + (size_t)l * HH, RC);
        gemm_wave<1><<<gupd, 256, 0, stream>>>(
            RC, Wat, nullptr, out, vbf, ba, (l == LL - 1) ? 1 : 0);
    }
}

// Round 15
// 1180.379 us; speedup vs baseline: 1.1934x; 1.1934x over previous
//
#include <hip/hip_runtime.h>
#include <hip/hip_bf16.h>
#include <math.h>

#define NND 100000   // nodes
#define EE  200000   // edges
#define LL  3        // layers
#define DD  300      // node dim
#define HH  150      // per-direction message dim

#define MPAD 100096  // 1564*64
#define KP   320     // K padded (multiple of 32)
#define NPJ  640     // proj N padded
#define NUP  384     // update N padded
#define NTK  (KP / 32)

#define NB   49          // scan blocks (2048 elems each)
#define SCN  (NB * 2048) // 100352 >= MPAD+1

// P column layout (all 8B-aligned region starts, pads zero):
//  Br @ 0..149 | Bc @ 152..301 | Ar @ 304..453 | Ac @ 456..605
#define P_BR 0
#define P_BC 152
#define P_AR 304
#define P_AC 456
// RC column layout: r @ 0..149, pad, c @ 160..309, pad
#define RC_R 0
#define RC_C 160

typedef __attribute__((ext_vector_type(8))) short bf16x8;
typedef __attribute__((ext_vector_type(4))) short bf16x4;
typedef __attribute__((ext_vector_type(4))) float f32x4;

__device__ __forceinline__ float gelu_exact(float z) {
    return 0.5f * z * (1.0f + erff(z * 0.7071067811865475f));
}
__device__ __forceinline__ unsigned short f2bf(float f) {
    union { float fv; unsigned u; } v; v.fv = f;
    unsigned r = v.u + 0x7fff + ((v.u >> 16) & 1);   // RNE (finite inputs)
    return (unsigned short)(r >> 16);
}
__device__ __forceinline__ float bf2f(unsigned short b) {
    union { unsigned u; float fv; } v; v.u = ((unsigned)b) << 16;
    return v.fv;
}

// ---------------- weight packing ----------------
__global__ __launch_bounds__(256) void pack_w(
    const float* __restrict__ Wr, const float* __restrict__ Wc,
    const float* __restrict__ Wa,
    unsigned short* __restrict__ Bt, unsigned short* __restrict__ Wat)
{
    int i = blockIdx.x * 256 + threadIdx.x;
    const int btTotal = LL * NPJ * KP;
    if (i < btTotal) {
        int l = i / (NPJ * KP);
        int rem = i % (NPJ * KP);
        int n = rem / KP;
        int k = rem % KP;
        float v = 0.f;
        if (k < DD) {
            const float* W = nullptr; int krow = k, j = -1;
            if (n >= P_BR && n < P_BR + 150)      { W = Wr; krow = 300 + k; j = n - P_BR; }
            else if (n >= P_BC && n < P_BC + 150) { W = Wc; krow = 300 + k; j = n - P_BC; }
            else if (n >= P_AR && n < P_AR + 150) { W = Wr; krow = k;       j = n - P_AR; }
            else if (n >= P_AC && n < P_AC + 150) { W = Wc; krow = k;       j = n - P_AC; }
            if (j >= 0)
                v = W[(size_t)l * 600 * 150 + (size_t)krow * 150 + j];
        }
        Bt[i] = f2bf(v);
    } else {
        int i2 = i - btTotal;
        if (i2 < NUP * KP) {
            int n = i2 / KP, k = i2 % KP;
            int kk = -1;
            if (k < 150)                 kk = k;          // r rows of Wa
            else if (k >= 160 && k < 310) kk = k - 10;    // c rows of Wa
            float v = (n < DD && kk >= 0) ? Wa[(size_t)kk * DD + n] : 0.f;
            Wat[i2] = f2bf(v);
        }
    }
}

// vbf[MPAD][KP] = bf16(x), zero pads
__global__ __launch_bounds__(256) void init_vbf(
    const float* __restrict__ x, unsigned short* __restrict__ vbf)
{
    int idx = blockIdx.x * 256 + threadIdx.x;       // chunk of 8
    int row = idx / (KP / 8);
    int gk  = (idx % (KP / 8)) * 8;
    if (row >= MPAD) return;
    unsigned short tmp[8];
    if (row < NND && gk < DD) {
        if (gk + 8 <= DD) {
            const float4* p = (const float4*)(x + (size_t)row * DD + gk);
            float4 f0 = p[0], f1 = p[1];
            tmp[0] = f2bf(f0.x); tmp[1] = f2bf(f0.y);
            tmp[2] = f2bf(f0.z); tmp[3] = f2bf(f0.w);
            tmp[4] = f2bf(f1.x); tmp[5] = f2bf(f1.y);
            tmp[6] = f2bf(f1.z); tmp[7] = f2bf(f1.w);
        } else {
            #pragma unroll
            for (int j = 0; j < 8; ++j)
                tmp[j] = (gk + j < DD) ? f2bf(x[(size_t)row * DD + gk + j]) : 0;
        }
    } else {
        #pragma unroll
        for (int j = 0; j < 8; ++j) tmp[j] = 0;
    }
    *((bf16x8*)&vbf[(size_t)row * KP + gk]) = *((bf16x8*)tmp);
}

// ---------------- CSR build ----------------
__global__ __launch_bounds__(256) void hist_deg(
    const int* __restrict__ src, const int* __restrict__ dst,
    int* __restrict__ deg)
{
    int e = blockIdx.x * 256 + threadIdx.x;
    if (e >= EE) return;
    atomicAdd(&deg[dst[e]], 1);
    atomicAdd(&deg[SCN + src[e]], 1);
}

__global__ __launch_bounds__(256) void scanA(
    const int* __restrict__ deg, int* __restrict__ off, int* __restrict__ bsum)
{
    __shared__ int ls[256];
    const int t = threadIdx.x, row = blockIdx.y;
    const int base = blockIdx.x * 2048 + t * 8;
    const int* dg = deg + (size_t)row * SCN + base;
    int v[8];
    #pragma unroll
    for (int j = 0; j < 8; ++j) v[j] = dg[j];
    int tot = 0;
    #pragma unroll
    for (int j = 0; j < 8; ++j) tot += v[j];
    ls[t] = tot;
    __syncthreads();
    #pragma unroll
    for (int d = 1; d < 256; d <<= 1) {
        int tv = (t >= d) ? ls[t - d] : 0;
        __syncthreads();
        ls[t] += tv;
        __syncthreads();
    }
    int run = ls[t] - tot;
    int* op = off + (size_t)row * SCN + base;
    #pragma unroll
    for (int j = 0; j < 8; ++j) { op[j] = run; run += v[j]; }
    if (t == 255) bsum[row * 64 + blockIdx.x] = ls[255];
}

__global__ __launch_bounds__(256) void scanB(int* __restrict__ bsum)
{
    if (threadIdx.x < 2) {
        int row = threadIdx.x, c = 0;
        for (int i = 0; i < NB; ++i) {
            int tv = bsum[row * 64 + i];
            bsum[row * 64 + i] = c;
            c += tv;
        }
    }
}

__global__ __launch_bounds__(256) void scanC(
    int* __restrict__ off, const int* __restrict__ bsum, int* __restrict__ cur)
{
    const int t = threadIdx.x, row = blockIdx.y;
    const int base = blockIdx.x * 2048 + t * 8;
    const int add = bsum[row * 64 + blockIdx.x];
    int* op = off + (size_t)row * SCN + base;
    int* cp = cur + (size_t)row * SCN + base;
    #pragma unroll
    for (int j = 0; j < 8; ++j) {
        int v = op[j] + add;
        op[j] = v;
        cp[j] = v;
    }
}

__global__ __launch_bounds__(256) void fill_adj(
    const int* __restrict__ src, const int* __restrict__ dst,
    int* __restrict__ cur, int* __restrict__ adj)
{
    int e = blockIdx.x * 256 + threadIdx.x;
    if (e >= EE) return;
    int s = src[e], d = dst[e];
    int pd = atomicAdd(&cur[d], 1);
    adj[pd] = s;
    int ps = atomicAdd(&cur[SCN + s], 1);
    adj[EE + ps] = d;
}

// ---------------- aggregation (no atomics, vectorized aligned gathers) ------
__global__ __launch_bounds__(256) void aggregate(
    const int* __restrict__ off, const int* __restrict__ adj,
    const unsigned short* __restrict__ P,
    const float* __restrict__ br, const float* __restrict__ bc,
    unsigned short* __restrict__ RC)
{
    const int n    = blockIdx.x * 4 + (threadIdx.x >> 6);
    const int dir  = blockIdx.y;
    const int lane = threadIdx.x & 63;
    const int c    = lane * 4;             // col base within 150-wide region

    if (lane < 10)
        RC[(size_t)n * KP + (dir ? 310 : 150) + lane] = 0;
    if (c >= 152) return;

    const int* offp = off + (size_t)dir * SCN;
    const int* adjp = adj + (size_t)dir * EE;
    const float* bias = dir ? bc : br;
    const unsigned short* own = P + (size_t)n * NPJ + (dir ? P_AC : P_AR);
    const int poff = dir ? P_BC : P_BR;

    const bool g0 = (c + 0) < 150, g1 = (c + 1) < 150;
    const bool g2 = (c + 2) < 150, g3 = (c + 3) < 150;

    bf16x4 ow = *((const bf16x4*)&own[c]);
    float o0 = bf2f((unsigned short)ow[0]) + (g0 ? bias[c + 0] : 0.f);
    float o1 = bf2f((unsigned short)ow[1]) + (g1 ? bias[c + 1] : 0.f);
    float o2 = bf2f((unsigned short)ow[2]) + (g2 ? bias[c + 2] : 0.f);
    float o3 = bf2f((unsigned short)ow[3]) + (g3 ? bias[c + 3] : 0.f);

    float s0 = 0.f, s1 = 0.f, s2 = 0.f, s3 = 0.f;
    int beg = offp[n], end = offp[n + 1];
    if (beg < end) {
        int a = adjp[beg];
        for (int i = beg; i < end; ++i) {
            int anext = (i + 1 < end) ? adjp[i + 1] : 0;
            const unsigned short* pp = P + (size_t)a * NPJ + poff;
            bf16x4 pv = *((const bf16x4*)&pp[c]);
            s0 += gelu_exact(o0 + bf2f((unsigned short)pv[0]));
            s1 += gelu_exact(o1 + bf2f((unsigned short)pv[1]));
            s2 += gelu_exact(o2 + bf2f((unsigned short)pv[2]));
            s3 += gelu_exact(o3 + bf2f((unsigned short)pv[3]));
            a = anext;
        }
    }
    unsigned short* outrow = RC + (size_t)n * KP + (dir ? RC_C : RC_R);
    if (c + 4 <= 150) {
        bf16x4 o;
        o[0] = (short)f2bf(s0); o[1] = (short)f2bf(s1);
        o[2] = (short)f2bf(s2); o[3] = (short)f2bf(s3);
        *((bf16x4*)&outrow[c]) = o;
    } else {
        if (g0) outrow[c + 0] = f2bf(s0);
        if (g1) outrow[c + 1] = f2bf(s1);
    }
}

// ---- wave-decoupled GEMM: B-in-regs (forced), wave-private A ring, 0 barriers
// Block 64r x 128c, wave = 64r x 32c. Each wave stages its OWN 64x32 A tile
// (4 x global_load_lds / step) into a private 16KB 4-buffer ring. Counted
// per-wave vmcnt waits; issue order pinned with sched_barrier.
#define GL(psrc, ldst) __builtin_amdgcn_global_load_lds( \
    (const __attribute__((address_space(1))) unsigned int*)(psrc), \
    (__attribute__((address_space(3))) unsigned int*)(ldst), 16, 0, 0)

#define SB0() __builtin_amdgcn_sched_barrier(0)

#define STAGEP(BUF, TT) do { \
    GL(p0 + (TT) * 32, Aw + (BUF) * 2048 + 0 * 512); \
    GL(p1 + (TT) * 32, Aw + (BUF) * 2048 + 1 * 512); \
    GL(p2 + (TT) * 32, Aw + (BUF) * 2048 + 2 * 512); \
    GL(p3 + (TT) * 32, Aw + (BUF) * 2048 + 3 * 512); \
    SB0(); } while (0)

// MODE 0: P[row*NPJ+col] = bf16(acc)
// MODE 1: nv = vbf_old + gelu(acc + bias[col]); last? out=fp32(nv) : vbf=bf16(nv)
template<int MODE>
__global__ __launch_bounds__(256, 2) void gemm_wavp(
    const unsigned short* __restrict__ Ab,
    const unsigned short* __restrict__ Bt,
    unsigned short* __restrict__ P,
    float* __restrict__ outv, unsigned short* __restrict__ vbf,
    const float* __restrict__ bias, int last)
{
    __shared__ unsigned short smem[4 * 8192];   // 64 KB: 16KB private ring/wave

    const int tid  = threadIdx.x;
    const int lane = tid & 63;
    const int wid  = tid >> 6;
    unsigned short* Aw = &smem[wid * 8192];

    // bijective XCD swizzle (m204)
    const int gx   = gridDim.x;
    const int nwg  = gx * gridDim.y;
    const int flat = blockIdx.y * gx + blockIdx.x;
    const int q = nwg >> 3, r = nwg & 7;
    const int xcd = flat & 7, off = flat >> 3;
    const int lid = (xcd < r ? xcd * (q + 1) : r * (q + 1) + (xcd - r) * q) + off;
    const int brow = (lid / gx) * 64;
    const int bcol = (lid % gx) * 128;
    const int wn   = wid * 32;

    // ---- B panel -> registers (20 x bf16x8 = 80 VGPR), once per block ----
    bf16x8 bfr[NTK][2];
    {
        const unsigned short* Bb =
            Bt + (size_t)(bcol + wn + (lane & 15)) * KP + (lane >> 4) * 8;
        #pragma unroll
        for (int t = 0; t < NTK; ++t) {
            bfr[t][0] = *((const bf16x8*)(Bb + t * 32));
            bfr[t][1] = *((const bf16x8*)(Bb + (size_t)16 * KP + t * 32));
        }
    }
    SB0();   // pin: all B loads issued before any stage

    // ---- private A staging pointers: load j covers rows j*16..j*16+15 ----
    // lane l -> row j*16 + (l>>2), source chunk c = (l&3) ^ ((row>>1)&3)
    const int r0 = (lane >> 2);
    const unsigned short* p0; const unsigned short* p1;
    const unsigned short* p2; const unsigned short* p3;
    {
        int rr0 = 0 * 16 + r0, rr1 = 1 * 16 + r0, rr2 = 2 * 16 + r0, rr3 = 3 * 16 + r0;
        int c0 = (lane & 3) ^ ((rr0 >> 1) & 3);
        int c1 = (lane & 3) ^ ((rr1 >> 1) & 3);
        int c2 = (lane & 3) ^ ((rr2 >> 1) & 3);
        int c3 = (lane & 3) ^ ((rr3 >> 1) & 3);
        p0 = Ab + (size_t)(brow + rr0) * KP + c0 * 8;
        p1 = Ab + (size_t)(brow + rr1) * KP + c1 * 8;
        p2 = Ab + (size_t)(brow + rr2) * KP + c2 * 8;
        p3 = Ab + (size_t)(brow + rr3) * KP + c3 * 8;
    }

    f32x4 acc[4][2];
    #pragma unroll
    for (int i = 0; i < 4; ++i)
        #pragma unroll
        for (int j = 0; j < 2; ++j)
            #pragma unroll
            for (int rr = 0; rr < 4; ++rr) acc[i][j][rr] = 0.f;

    // prologue: stage tiles 0,1,2 into private ring
    STAGEP(0, 0); STAGEP(1, 1); STAGEP(2, 2);

    #pragma unroll
    for (int t = 0; t < NTK; ++t) {
        if (t + 3 < NTK) STAGEP((t + 3) & 3, t + 3);
        // per-wave counted wait: tile t's 4 loads are the oldest remaining
        if (t <= NTK - 4)      { asm volatile("s_waitcnt vmcnt(12)" ::: "memory"); }
        else if (t == NTK - 3) { asm volatile("s_waitcnt vmcnt(8)"  ::: "memory"); }
        else if (t == NTK - 2) { asm volatile("s_waitcnt vmcnt(4)"  ::: "memory"); }
        else                   { asm volatile("s_waitcnt vmcnt(0)"  ::: "memory"); }
        SB0();

        const unsigned short* Alc = Aw + (t & 3) * 2048;
        bf16x8 af[4];
        #pragma unroll
        for (int mi = 0; mi < 4; ++mi) {
            int row = mi * 16 + (lane & 15);
            af[mi] = *((const bf16x8*)&Alc[row * 32 +
                       (((lane >> 4) ^ ((row >> 1) & 3)) * 8)]);
        }
        __builtin_amdgcn_s_setprio(1);
        #pragma unroll
        for (int mi = 0; mi < 4; ++mi)
            #pragma unroll
            for (int nj = 0; nj < 2; ++nj)
                acc[mi][nj] = __builtin_amdgcn_mfma_f32_16x16x32_bf16(
                    af[mi], bfr[t][nj], acc[mi][nj], 0, 0, 0);
        __builtin_amdgcn_s_setprio(0);
    }
    // all staging landed (vmcnt(0) at t=9); ring is reusable as private bounce

    if (MODE == 0) {
        // bf16 bounce [64][40] in own ring (5120 shorts <= 8192)
        #pragma unroll
        for (int mi = 0; mi < 4; ++mi)
            #pragma unroll
            for (int nj = 0; nj < 2; ++nj)
                #pragma unroll
                for (int rr = 0; rr < 4; ++rr) {
                    int row = mi * 16 + ((lane >> 4) << 2) + rr;
                    int col = nj * 16 + (lane & 15);
                    Aw[row * 40 + col] = f2bf(acc[mi][nj][rr]);
                }
        #pragma unroll
        for (int i = 0; i < 4; ++i) {
            int row = i * 16 + (lane >> 2);
            bf16x8 v = *((const bf16x8*)&Aw[row * 40 + (lane & 3) * 8]);
            *((bf16x8*)&P[(size_t)(brow + row) * NPJ + bcol + wn + (lane & 3) * 8]) = v;
        }
    } else {
        // fp32 bounce [64][36] in own ring (9216 floats bytes = 9216*... 64*36*4B = 9216B <= 16384)
        float* fb = (float*)Aw;
        #pragma unroll
        for (int mi = 0; mi < 4; ++mi)
            #pragma unroll
            for (int nj = 0; nj < 2; ++nj)
                #pragma unroll
                for (int rr = 0; rr < 4; ++rr) {
                    int row = mi * 16 + ((lane >> 4) << 2) + rr;
                    int col = nj * 16 + (lane & 15);
                    fb[row * 36 + col] = acc[mi][nj][rr];
                }
        const int gc = bcol + wn + (lane & 7) * 4;
        #pragma unroll
        for (int i = 0; i < 8; ++i) {
            int row = i * 8 + (lane >> 3);
            int grow = brow + row;
            float4 vv = *((const float4*)&fb[row * 36 + (lane & 7) * 4]);
            if (grow < NND) {
                if (gc + 4 <= DD) {
                    float4 bv = *((const float4*)&bias[gc]);
                    bf16x4 old = *((const bf16x4*)&vbf[(size_t)grow * KP + gc]);
                    float4 nv;
                    nv.x = bf2f((unsigned short)old[0]) + gelu_exact(vv.x + bv.x);
                    nv.y = bf2f((unsigned short)old[1]) + gelu_exact(vv.y + bv.y);
                    nv.z = bf2f((unsigned short)old[2]) + gelu_exact(vv.z + bv.z);
                    nv.w = bf2f((unsigned short)old[3]) + gelu_exact(vv.w + bv.w);
                    if (last) {
                        *((float4*)&outv[(size_t)grow * DD + gc]) = nv;
                    } else {
                        bf16x4 o;
                        o[0] = (short)f2bf(nv.x); o[1] = (short)f2bf(nv.y);
                        o[2] = (short)f2bf(nv.z); o[3] = (short)f2bf(nv.w);
                        *((bf16x4*)&vbf[(size_t)grow * KP + gc]) = o;
                    }
                } else {
                    #pragma unroll
                    for (int j = 0; j < 4; ++j) {
                        int ccc = gc + j;
                        if (ccc < DD) {
                            float vj = (j == 0) ? vv.x : (j == 1) ? vv.y
                                     : (j == 2) ? vv.z : vv.w;
                            size_t vidx = (size_t)grow * KP + ccc;
                            float nv = bf2f(vbf[vidx]) + gelu_exact(vj + bias[ccc]);
                            if (last) outv[(size_t)grow * DD + ccc] = nv;
                            else      vbf[vidx] = f2bf(nv);
                        }
                    }
                }
            }
        }
    }
}

extern "C" void kernel_launch(void* const* d_in, const int* in_sizes, int n_in,
                              void* d_out, int out_size, void* d_ws, size_t ws_size,
                              hipStream_t stream) {
    const float* x  = (const float*)d_in[0];
    const int*   ei = (const int*)  d_in[1];
    const float* Wr = (const float*)d_in[2];
    const float* br = (const float*)d_in[3];
    const float* Wc = (const float*)d_in[4];
    const float* bc = (const float*)d_in[5];
    const float* Wa = (const float*)d_in[6];
    const float* ba = (const float*)d_in[7];
    float* out = (float*)d_out;

    const size_t P_elems   = (size_t)MPAD * NPJ;   // bf16
    const size_t RC_elems  = (size_t)MPAD * KP;    // bf16
    const size_t V_elems   = (size_t)MPAD * KP;    // bf16
    const size_t Bt_elems  = (size_t)LL * NPJ * KP;
    const size_t Wat_elems = (size_t)NUP * KP;

    unsigned short* P   = (unsigned short*)d_ws;
    unsigned short* RC  = P + P_elems;
    unsigned short* vbf = RC + RC_elems;
    unsigned short* Bt  = vbf + V_elems;
    unsigned short* Wat = Bt + Bt_elems;
    int* deg  = (int*)(Wat + Wat_elems);
    int* off  = deg + 2 * SCN;
    int* curp = off + 2 * SCN;
    int* adj  = curp + 2 * SCN;
    int* bsum = adj + 2 * EE;
    const size_t need = (char*)(bsum + 128) - (char*)d_ws;
    if (ws_size < need) return;  // visible fail (output stays poisoned)

    pack_w<<<2880, 256, 0, stream>>>(Wr, Wc, Wa, Bt, Wat);
    init_vbf<<<(int)((V_elems / 8 + 255) / 256), 256, 0, stream>>>(x, vbf);

    const int* src = ei;
    const int* dst = ei + EE;

    hipMemsetAsync(deg, 0, 2 * SCN * sizeof(int), stream);
    hist_deg<<<(EE + 255) / 256, 256, 0, stream>>>(src, dst, deg);
    scanA<<<dim3(NB, 2), 256, 0, stream>>>(deg, off, bsum);
    scanB<<<1, 256, 0, stream>>>(bsum);
    scanC<<<dim3(NB, 2), 256, 0, stream>>>(off, bsum, curp);
    fill_adj<<<(EE + 255) / 256, 256, 0, stream>>>(src, dst, curp, adj);

    dim3 gproj(NPJ / 128, MPAD / 64);   // (5, 1564)
    dim3 gupd (NUP / 128, MPAD / 64);   // (3, 1564)
    dim3 gagg (MPAD / 4, 2);

    for (int l = 0; l < LL; ++l) {
        gemm_wavp<0><<<gproj, 256, 0, stream>>>(
            vbf, Bt + (size_t)l * NPJ * KP, P, nullptr, nullptr, nullptr, 0);
        aggregate<<<gagg, 256, 0, stream>>>(
            off, adj, P, br + (size_t)l * HH, bc + (size_t)l * HH, RC);
        gemm_wavp<1><<<gupd, 256, 0, stream>>>(
            RC, Wat, nullptr, out, vbf, ba, (l == LL - 1) ? 1 : 0);
    }
}

// Round 16
// 978.894 us; speedup vs baseline: 1.4391x; 1.2058x over previous
//
#include <hip/hip_runtime.h>
#include <hip/hip_bf16.h>
#include <math.h>

#define NND 100000   // nodes
#define EE  200000   // edges
#define LL  3        // layers
#define DD  300      // node dim
#define HH  150      // per-direction message dim

#define MPAD 100096  // 1564*64
#define KP   320     // K padded (multiple of 32)
#define NPJ  640     // proj N padded
#define NUP  384     // update N padded
#define NTK  (KP / 32)

#define NB   49          // scan blocks (2048 elems each)
#define SCN  (NB * 2048) // 100352 >= MPAD+1

// P column layout (all 8B-aligned region starts, pads zero):
//  Br @ 0..149 | Bc @ 152..301 | Ar @ 304..453 | Ac @ 456..605
#define P_BR 0
#define P_BC 152
#define P_AR 304
#define P_AC 456
// RC column layout: r @ 0..149, pad, c @ 160..309, pad
#define RC_R 0
#define RC_C 160

typedef __attribute__((ext_vector_type(8))) short bf16x8;
typedef __attribute__((ext_vector_type(4))) short bf16x4;
typedef __attribute__((ext_vector_type(4))) float f32x4;

__device__ __forceinline__ float gelu_exact(float z) {
    return 0.5f * z * (1.0f + erff(z * 0.7071067811865475f));
}
__device__ __forceinline__ unsigned short f2bf(float f) {
    union { float fv; unsigned u; } v; v.fv = f;
    unsigned r = v.u + 0x7fff + ((v.u >> 16) & 1);   // RNE (finite inputs)
    return (unsigned short)(r >> 16);
}
__device__ __forceinline__ float bf2f(unsigned short b) {
    union { unsigned u; float fv; } v; v.u = ((unsigned)b) << 16;
    return v.fv;
}

// ---------------- weight packing ----------------
__global__ __launch_bounds__(256) void pack_w(
    const float* __restrict__ Wr, const float* __restrict__ Wc,
    const float* __restrict__ Wa,
    unsigned short* __restrict__ Bt, unsigned short* __restrict__ Wat)
{
    int i = blockIdx.x * 256 + threadIdx.x;
    const int btTotal = LL * NPJ * KP;
    if (i < btTotal) {
        int l = i / (NPJ * KP);
        int rem = i % (NPJ * KP);
        int n = rem / KP;
        int k = rem % KP;
        float v = 0.f;
        if (k < DD) {
            const float* W = nullptr; int krow = k, j = -1;
            if (n >= P_BR && n < P_BR + 150)      { W = Wr; krow = 300 + k; j = n - P_BR; }
            else if (n >= P_BC && n < P_BC + 150) { W = Wc; krow = 300 + k; j = n - P_BC; }
            else if (n >= P_AR && n < P_AR + 150) { W = Wr; krow = k;       j = n - P_AR; }
            else if (n >= P_AC && n < P_AC + 150) { W = Wc; krow = k;       j = n - P_AC; }
            if (j >= 0)
                v = W[(size_t)l * 600 * 150 + (size_t)krow * 150 + j];
        }
        Bt[i] = f2bf(v);
    } else {
        int i2 = i - btTotal;
        if (i2 < NUP * KP) {
            int n = i2 / KP, k = i2 % KP;
            int kk = -1;
            if (k < 150)                 kk = k;          // r rows of Wa
            else if (k >= 160 && k < 310) kk = k - 10;    // c rows of Wa
            float v = (n < DD && kk >= 0) ? Wa[(size_t)kk * DD + n] : 0.f;
            Wat[i2] = f2bf(v);
        }
    }
}

// vbf[MPAD][KP] = bf16(x), zero pads
__global__ __launch_bounds__(256) void init_vbf(
    const float* __restrict__ x, unsigned short* __restrict__ vbf)
{
    int idx = blockIdx.x * 256 + threadIdx.x;       // chunk of 8
    int row = idx / (KP / 8);
    int gk  = (idx % (KP / 8)) * 8;
    if (row >= MPAD) return;
    unsigned short tmp[8];
    if (row < NND && gk < DD) {
        if (gk + 8 <= DD) {
            const float4* p = (const float4*)(x + (size_t)row * DD + gk);
            float4 f0 = p[0], f1 = p[1];
            tmp[0] = f2bf(f0.x); tmp[1] = f2bf(f0.y);
            tmp[2] = f2bf(f0.z); tmp[3] = f2bf(f0.w);
            tmp[4] = f2bf(f1.x); tmp[5] = f2bf(f1.y);
            tmp[6] = f2bf(f1.z); tmp[7] = f2bf(f1.w);
        } else {
            #pragma unroll
            for (int j = 0; j < 8; ++j)
                tmp[j] = (gk + j < DD) ? f2bf(x[(size_t)row * DD + gk + j]) : 0;
        }
    } else {
        #pragma unroll
        for (int j = 0; j < 8; ++j) tmp[j] = 0;
    }
    *((bf16x8*)&vbf[(size_t)row * KP + gk]) = *((bf16x8*)tmp);
}

// ---------------- CSR build ----------------
__global__ __launch_bounds__(256) void hist_deg(
    const int* __restrict__ src, const int* __restrict__ dst,
    int* __restrict__ deg)
{
    int e = blockIdx.x * 256 + threadIdx.x;
    if (e >= EE) return;
    atomicAdd(&deg[dst[e]], 1);
    atomicAdd(&deg[SCN + src[e]], 1);
}

__global__ __launch_bounds__(256) void scanA(
    const int* __restrict__ deg, int* __restrict__ off, int* __restrict__ bsum)
{
    __shared__ int ls[256];
    const int t = threadIdx.x, row = blockIdx.y;
    const int base = blockIdx.x * 2048 + t * 8;
    const int* dg = deg + (size_t)row * SCN + base;
    int v[8];
    #pragma unroll
    for (int j = 0; j < 8; ++j) v[j] = dg[j];
    int tot = 0;
    #pragma unroll
    for (int j = 0; j < 8; ++j) tot += v[j];
    ls[t] = tot;
    __syncthreads();
    #pragma unroll
    for (int d = 1; d < 256; d <<= 1) {
        int tv = (t >= d) ? ls[t - d] : 0;
        __syncthreads();
        ls[t] += tv;
        __syncthreads();
    }
    int run = ls[t] - tot;
    int* op = off + (size_t)row * SCN + base;
    #pragma unroll
    for (int j = 0; j < 8; ++j) { op[j] = run; run += v[j]; }
    if (t == 255) bsum[row * 64 + blockIdx.x] = ls[255];
}

__global__ __launch_bounds__(256) void scanB(int* __restrict__ bsum)
{
    if (threadIdx.x < 2) {
        int row = threadIdx.x, c = 0;
        for (int i = 0; i < NB; ++i) {
            int tv = bsum[row * 64 + i];
            bsum[row * 64 + i] = c;
            c += tv;
        }
    }
}

__global__ __launch_bounds__(256) void scanC(
    int* __restrict__ off, const int* __restrict__ bsum, int* __restrict__ cur)
{
    const int t = threadIdx.x, row = blockIdx.y;
    const int base = blockIdx.x * 2048 + t * 8;
    const int add = bsum[row * 64 + blockIdx.x];
    int* op = off + (size_t)row * SCN + base;
    int* cp = cur + (size_t)row * SCN + base;
    #pragma unroll
    for (int j = 0; j < 8; ++j) {
        int v = op[j] + add;
        op[j] = v;
        cp[j] = v;
    }
}

__global__ __launch_bounds__(256) void fill_adj(
    const int* __restrict__ src, const int* __restrict__ dst,
    int* __restrict__ cur, int* __restrict__ adj)
{
    int e = blockIdx.x * 256 + threadIdx.x;
    if (e >= EE) return;
    int s = src[e], d = dst[e];
    int pd = atomicAdd(&cur[d], 1);
    adj[pd] = s;
    int ps = atomicAdd(&cur[SCN + s], 1);
    adj[EE + ps] = d;
}

// ---------------- aggregation (no atomics, vectorized aligned gathers) ------
__global__ __launch_bounds__(256) void aggregate(
    const int* __restrict__ off, const int* __restrict__ adj,
    const unsigned short* __restrict__ P,
    const float* __restrict__ br, const float* __restrict__ bc,
    unsigned short* __restrict__ RC)
{
    const int n    = blockIdx.x * 4 + (threadIdx.x >> 6);
    const int dir  = blockIdx.y;
    const int lane = threadIdx.x & 63;
    const int c    = lane * 4;             // col base within 150-wide region

    if (lane < 10)
        RC[(size_t)n * KP + (dir ? 310 : 150) + lane] = 0;
    if (c >= 152) return;

    const int* offp = off + (size_t)dir * SCN;
    const int* adjp = adj + (size_t)dir * EE;
    const float* bias = dir ? bc : br;
    const unsigned short* own = P + (size_t)n * NPJ + (dir ? P_AC : P_AR);
    const int poff = dir ? P_BC : P_BR;

    const bool g0 = (c + 0) < 150, g1 = (c + 1) < 150;
    const bool g2 = (c + 2) < 150, g3 = (c + 3) < 150;

    bf16x4 ow = *((const bf16x4*)&own[c]);
    float o0 = bf2f((unsigned short)ow[0]) + (g0 ? bias[c + 0] : 0.f);
    float o1 = bf2f((unsigned short)ow[1]) + (g1 ? bias[c + 1] : 0.f);
    float o2 = bf2f((unsigned short)ow[2]) + (g2 ? bias[c + 2] : 0.f);
    float o3 = bf2f((unsigned short)ow[3]) + (g3 ? bias[c + 3] : 0.f);

    float s0 = 0.f, s1 = 0.f, s2 = 0.f, s3 = 0.f;
    int beg = offp[n], end = offp[n + 1];
    if (beg < end) {
        int a = adjp[beg];
        for (int i = beg; i < end; ++i) {
            int anext = (i + 1 < end) ? adjp[i + 1] : 0;
            const unsigned short* pp = P + (size_t)a * NPJ + poff;
            bf16x4 pv = *((const bf16x4*)&pp[c]);
            s0 += gelu_exact(o0 + bf2f((unsigned short)pv[0]));
            s1 += gelu_exact(o1 + bf2f((unsigned short)pv[1]));
            s2 += gelu_exact(o2 + bf2f((unsigned short)pv[2]));
            s3 += gelu_exact(o3 + bf2f((unsigned short)pv[3]));
            a = anext;
        }
    }
    unsigned short* outrow = RC + (size_t)n * KP + (dir ? RC_C : RC_R);
    if (c + 4 <= 150) {
        bf16x4 o;
        o[0] = (short)f2bf(s0); o[1] = (short)f2bf(s1);
        o[2] = (short)f2bf(s2); o[3] = (short)f2bf(s3);
        *((bf16x4*)&outrow[c]) = o;
    } else {
        if (g0) outrow[c + 0] = f2bf(s0);
        if (g1) outrow[c + 1] = f2bf(s1);
    }
}

// -------- low-LDS GEMM (R11 structure, 20.5 KB LDS): tile 64x128, 4 waves ----
// Block-wide A-ring 16KB (1 gload_lds/wave/step, vmcnt 2/1/0, 1 barrier/step);
// per-wave 5KB epilogue bounce overlapping the ring. 8 blocks/CU LDS-wise.
#define GLOAD16(gp, lp) __builtin_amdgcn_global_load_lds( \
    (const __attribute__((address_space(1))) unsigned int*)(gp), \
    (__attribute__((address_space(3))) unsigned int*)(lp), 16, 0, 0)

// MODE 0: P[row*NPJ+col] = bf16(acc)
// MODE 1: nv = vbf_old + gelu(acc + bias[col]); last? out=fp32(nv) : vbf=bf16(nv)
template<int MODE>
__global__ __launch_bounds__(256) void gemm_lo(
    const unsigned short* __restrict__ Ab,
    const unsigned short* __restrict__ Bt,
    unsigned short* __restrict__ P,
    float* __restrict__ outv, unsigned short* __restrict__ vbf,
    const float* __restrict__ bias, int last)
{
    __shared__ unsigned short smem[10240];         // 20480 B total
    unsigned short* Alds = smem;                   // ring: 4 x 2048 shorts (16KB)

    const int tid  = threadIdx.x;
    const int lane = tid & 63;
    const int wid  = tid >> 6;

    // bijective XCD swizzle (m204)
    const int gx   = gridDim.x;
    const int nwg  = gx * gridDim.y;
    const int flat = blockIdx.y * gx + blockIdx.x;
    const int q = nwg >> 3, r = nwg & 7;
    const int xcd = flat & 7, off = flat >> 3;
    const int lid = (xcd < r ? xcd * (q + 1) : r * (q + 1) + (xcd - r) * q) + off;
    const int brow = (lid / gx) * 64;
    const int bcol = (lid % gx) * 128;
    const int wn   = wid * 32;

    f32x4 acc[4][2];
    #pragma unroll
    for (int i = 0; i < 4; ++i)
        #pragma unroll
        for (int j = 0; j < 2; ++j)
            #pragma unroll
            for (int rr = 0; rr < 4; ++rr) acc[i][j][rr] = 0.f;

    // ---- B panel fragments (compiler chooses reg/reload; R11-proven) ----
    bf16x8 bfr[NTK][2];
    const unsigned short* Bb =
        Bt + (size_t)(bcol + wn + (lane & 15)) * KP + (lane >> 4) * 8;
    #pragma unroll
    for (int t = 0; t < NTK; ++t) {
        bfr[t][0] = *((const bf16x8*)(Bb + t * 32));
        bfr[t][1] = *((const bf16x8*)(Bb + (size_t)16 * KP + t * 32));
    }

    // per-thread A staging coords (chunk = tid; 64 rows x 4 chunks of 16B)
    const int arow = tid >> 2;
    const int ac   = (tid & 3) ^ ((arow >> 1) & 3);   // swizzled source chunk
    const unsigned short* asrc = Ab + (size_t)(brow + arow) * KP + ac * 8;

    // prologue: stage A tiles 0,1,2 (1 vmem op per wave per tile)
    #pragma unroll
    for (int t = 0; t < 3; ++t)
        GLOAD16(asrc + t * 32, Alds + t * 2048 + wid * 512);

    #pragma unroll
    for (int t = 0; t < NTK; ++t) {
        unsigned short* Alc = Alds + (t & 3) * 2048;
        if (t + 2 < NTK) {
            asm volatile("s_waitcnt vmcnt(2)" ::: "memory");
        } else if (t + 1 < NTK) {
            asm volatile("s_waitcnt vmcnt(1)" ::: "memory");
        } else {
            asm volatile("s_waitcnt vmcnt(0)" ::: "memory");
        }
        __builtin_amdgcn_s_barrier();
        // stage t+3 into buf (t+3)&3 = (t-1)&3: safe, barrier implies iter t-1
        // reads completed on all waves
        if (t + 3 < NTK)
            GLOAD16(asrc + (t + 3) * 32, Alds + ((t + 3) & 3) * 2048 + wid * 512);

        bf16x8 af[4];
        #pragma unroll
        for (int mi = 0; mi < 4; ++mi) {
            int row = mi * 16 + (lane & 15);
            af[mi] = *((const bf16x8*)&Alc[row * 32 + (((lane >> 4) ^ ((row >> 1) & 3)) * 8)]);
        }
        __builtin_amdgcn_s_setprio(1);
        #pragma unroll
        for (int mi = 0; mi < 4; ++mi)
            #pragma unroll
            for (int nj = 0; nj < 2; ++nj)
                acc[mi][nj] = __builtin_amdgcn_mfma_f32_16x16x32_bf16(
                    af[mi], bfr[t][nj], acc[mi][nj], 0, 0, 0);
        __builtin_amdgcn_s_setprio(0);
    }
    __syncthreads();   // all waves done with A ring before per-wave bounce reuse

    if (MODE == 0) {
        // per-wave bf16 bounce [64][40] = 2560 shorts at smem + wid*2560
        unsigned short* sb = &smem[wid * 2560];
        #pragma unroll
        for (int mi = 0; mi < 4; ++mi)
            #pragma unroll
            for (int nj = 0; nj < 2; ++nj)
                #pragma unroll
                for (int rr = 0; rr < 4; ++rr) {
                    int row = mi * 16 + ((lane >> 4) << 2) + rr;
                    sb[row * 40 + nj * 16 + (lane & 15)] = f2bf(acc[mi][nj][rr]);
                }
        #pragma unroll
        for (int i = 0; i < 4; ++i) {
            int row = i * 16 + (lane >> 2);
            bf16x8 v = *((const bf16x8*)&sb[row * 40 + (lane & 3) * 8]);
            *((bf16x8*)&P[(size_t)(brow + row) * NPJ + bcol + wn + (lane & 3) * 8]) = v;
        }
    } else {
        // per-wave fp32 bounce [32][40] = 5120B, two 32-row passes
        float* fb = (float*)&smem[wid * 2560];
        const int gc = bcol + wn + (lane & 7) * 4;
        #pragma unroll
        for (int h = 0; h < 2; ++h) {
            #pragma unroll
            for (int mi2 = 0; mi2 < 2; ++mi2)
                #pragma unroll
                for (int nj = 0; nj < 2; ++nj)
                    #pragma unroll
                    for (int rr = 0; rr < 4; ++rr) {
                        int row32 = mi2 * 16 + ((lane >> 4) << 2) + rr;
                        fb[row32 * 40 + nj * 16 + (lane & 15)] = acc[h * 2 + mi2][nj][rr];
                    }
            #pragma unroll
            for (int i = 0; i < 4; ++i) {
                int row32 = i * 8 + (lane >> 3);
                int grow = brow + h * 32 + row32;
                float4 vv = *((const float4*)&fb[row32 * 40 + (lane & 7) * 4]);
                if (grow < NND) {
                    if (gc + 4 <= DD) {
                        float4 bv = *((const float4*)&bias[gc]);
                        bf16x4 old = *((const bf16x4*)&vbf[(size_t)grow * KP + gc]);
                        float4 nv;
                        nv.x = bf2f((unsigned short)old[0]) + gelu_exact(vv.x + bv.x);
                        nv.y = bf2f((unsigned short)old[1]) + gelu_exact(vv.y + bv.y);
                        nv.z = bf2f((unsigned short)old[2]) + gelu_exact(vv.z + bv.z);
                        nv.w = bf2f((unsigned short)old[3]) + gelu_exact(vv.w + bv.w);
                        if (last) {
                            *((float4*)&outv[(size_t)grow * DD + gc]) = nv;
                        } else {
                            bf16x4 o;
                            o[0] = (short)f2bf(nv.x); o[1] = (short)f2bf(nv.y);
                            o[2] = (short)f2bf(nv.z); o[3] = (short)f2bf(nv.w);
                            *((bf16x4*)&vbf[(size_t)grow * KP + gc]) = o;
                        }
                    } else {
                        #pragma unroll
                        for (int j = 0; j < 4; ++j) {
                            int ccc = gc + j;
                            if (ccc < DD) {
                                float vj = (j == 0) ? vv.x : (j == 1) ? vv.y
                                         : (j == 2) ? vv.z : vv.w;
                                size_t vidx = (size_t)grow * KP + ccc;
                                float nv = bf2f(vbf[vidx]) + gelu_exact(vj + bias[ccc]);
                                if (last) outv[(size_t)grow * DD + ccc] = nv;
                                else      vbf[vidx] = f2bf(nv);
                            }
                        }
                    }
                }
            }
        }
    }
}

extern "C" void kernel_launch(void* const* d_in, const int* in_sizes, int n_in,
                              void* d_out, int out_size, void* d_ws, size_t ws_size,
                              hipStream_t stream) {
    const float* x  = (const float*)d_in[0];
    const int*   ei = (const int*)  d_in[1];
    const float* Wr = (const float*)d_in[2];
    const float* br = (const float*)d_in[3];
    const float* Wc = (const float*)d_in[4];
    const float* bc = (const float*)d_in[5];
    const float* Wa = (const float*)d_in[6];
    const float* ba = (const float*)d_in[7];
    float* out = (float*)d_out;

    const size_t P_elems   = (size_t)MPAD * NPJ;   // bf16
    const size_t RC_elems  = (size_t)MPAD * KP;    // bf16
    const size_t V_elems   = (size_t)MPAD * KP;    // bf16
    const size_t Bt_elems  = (size_t)LL * NPJ * KP;
    const size_t Wat_elems = (size_t)NUP * KP;

    unsigned short* P   = (unsigned short*)d_ws;
    unsigned short* RC  = P + P_elems;
    unsigned short* vbf = RC + RC_elems;
    unsigned short* Bt  = vbf + V_elems;
    unsigned short* Wat = Bt + Bt_elems;
    int* deg  = (int*)(Wat + Wat_elems);
    int* off  = deg + 2 * SCN;
    int* curp = off + 2 * SCN;
    int* adj  = curp + 2 * SCN;
    int* bsum = adj + 2 * EE;
    const size_t need = (char*)(bsum + 128) - (char*)d_ws;
    if (ws_size < need) return;  // visible fail (output stays poisoned)

    pack_w<<<2880, 256, 0, stream>>>(Wr, Wc, Wa, Bt, Wat);
    init_vbf<<<(int)((V_elems / 8 + 255) / 256), 256, 0, stream>>>(x, vbf);

    const int* src = ei;
    const int* dst = ei + EE;

    hipMemsetAsync(deg, 0, 2 * SCN * sizeof(int), stream);
    hist_deg<<<(EE + 255) / 256, 256, 0, stream>>>(src, dst, deg);
    scanA<<<dim3(NB, 2), 256, 0, stream>>>(deg, off, bsum);
    scanB<<<1, 256, 0, stream>>>(bsum);
    scanC<<<dim3(NB, 2), 256, 0, stream>>>(off, bsum, curp);
    fill_adj<<<(EE + 255) / 256, 256, 0, stream>>>(src, dst, curp, adj);

    dim3 gproj(NPJ / 128, MPAD / 64);   // (5, 1564)
    dim3 gupd (NUP / 128, MPAD / 64);   // (3, 1564)
    dim3 gagg (MPAD / 4, 2);

    for (int l = 0; l < LL; ++l) {
        gemm_lo<0><<<gproj, 256, 0, stream>>>(
            vbf, Bt + (size_t)l * NPJ * KP, P, nullptr, nullptr, nullptr, 0);
        aggregate<<<gagg, 256, 0, stream>>>(
            off, adj, P, br + (size_t)l * HH, bc + (size_t)l * HH, RC);
        gemm_lo<1><<<gupd, 256, 0, stream>>>(
            RC, Wat, nullptr, out, vbf, ba, (l == LL - 1) ? 1 : 0);
    }
}

// Round 17
// 857.178 us; speedup vs baseline: 1.6434x; 1.1420x over previous
//
#include <hip/hip_runtime.h>
#include <hip/hip_bf16.h>
#include <math.h>

#define NND 100000   // nodes
#define EE  200000   // edges
#define LL  3        // layers
#define DD  300      // node dim
#define HH  150      // per-direction message dim

#define MPAD 100096  // 1564*64
#define KP   320     // K padded (multiple of 32)
#define NPJ  640     // proj N padded
#define NUP  384     // update N padded
#define NTK  (KP / 32)

#define NB   49          // scan blocks (2048 elems each)
#define SCN  (NB * 2048) // 100352 >= MPAD+1

// P column layout (all 8B-aligned region starts, pads zero):
//  Br @ 0..149 | Bc @ 152..301 | Ar @ 304..453 | Ac @ 456..605
#define P_BR 0
#define P_BC 152
#define P_AR 304
#define P_AC 456
// RC column layout: r @ 0..149, pad, c @ 160..309, pad
#define RC_R 0
#define RC_C 160

typedef __attribute__((ext_vector_type(8))) short bf16x8;
typedef __attribute__((ext_vector_type(4))) short bf16x4;
typedef __attribute__((ext_vector_type(4))) float f32x4;

// fast GELU (tanh-form): max abs dev from exact-erf GELU ~1e-3.
// gelu(x) = x * sigmoid(2*0.7978845608*(x + 0.044715 x^3))
__device__ __forceinline__ float gelu_exact(float x) {
    float x2 = x * x;
    float y2 = -1.5957691216f * (x + 0.044715f * x2 * x);
    float e  = __expf(y2);                       // v_exp_f32 (+scale)
    return x * __builtin_amdgcn_rcpf(1.f + e);   // v_rcp_f32
}
__device__ __forceinline__ unsigned short f2bf(float f) {
    union { float fv; unsigned u; } v; v.fv = f;
    unsigned r = v.u + 0x7fff + ((v.u >> 16) & 1);   // RNE (finite inputs)
    return (unsigned short)(r >> 16);
}
__device__ __forceinline__ float bf2f(unsigned short b) {
    union { unsigned u; float fv; } v; v.u = ((unsigned)b) << 16;
    return v.fv;
}

// ---------------- weight packing ----------------
__global__ __launch_bounds__(256) void pack_w(
    const float* __restrict__ Wr, const float* __restrict__ Wc,
    const float* __restrict__ Wa,
    unsigned short* __restrict__ Bt, unsigned short* __restrict__ Wat)
{
    int i = blockIdx.x * 256 + threadIdx.x;
    const int btTotal = LL * NPJ * KP;
    if (i < btTotal) {
        int l = i / (NPJ * KP);
        int rem = i % (NPJ * KP);
        int n = rem / KP;
        int k = rem % KP;
        float v = 0.f;
        if (k < DD) {
            const float* W = nullptr; int krow = k, j = -1;
            if (n >= P_BR && n < P_BR + 150)      { W = Wr; krow = 300 + k; j = n - P_BR; }
            else if (n >= P_BC && n < P_BC + 150) { W = Wc; krow = 300 + k; j = n - P_BC; }
            else if (n >= P_AR && n < P_AR + 150) { W = Wr; krow = k;       j = n - P_AR; }
            else if (n >= P_AC && n < P_AC + 150) { W = Wc; krow = k;       j = n - P_AC; }
            if (j >= 0)
                v = W[(size_t)l * 600 * 150 + (size_t)krow * 150 + j];
        }
        Bt[i] = f2bf(v);
    } else {
        int i2 = i - btTotal;
        if (i2 < NUP * KP) {
            int n = i2 / KP, k = i2 % KP;
            int kk = -1;
            if (k < 150)                 kk = k;          // r rows of Wa
            else if (k >= 160 && k < 310) kk = k - 10;    // c rows of Wa
            float v = (n < DD && kk >= 0) ? Wa[(size_t)kk * DD + n] : 0.f;
            Wat[i2] = f2bf(v);
        }
    }
}

// vbf[MPAD][KP] = bf16(x), zero pads
__global__ __launch_bounds__(256) void init_vbf(
    const float* __restrict__ x, unsigned short* __restrict__ vbf)
{
    int idx = blockIdx.x * 256 + threadIdx.x;       // chunk of 8
    int row = idx / (KP / 8);
    int gk  = (idx % (KP / 8)) * 8;
    if (row >= MPAD) return;
    unsigned short tmp[8];
    if (row < NND && gk < DD) {
        if (gk + 8 <= DD) {
            const float4* p = (const float4*)(x + (size_t)row * DD + gk);
            float4 f0 = p[0], f1 = p[1];
            tmp[0] = f2bf(f0.x); tmp[1] = f2bf(f0.y);
            tmp[2] = f2bf(f0.z); tmp[3] = f2bf(f0.w);
            tmp[4] = f2bf(f1.x); tmp[5] = f2bf(f1.y);
            tmp[6] = f2bf(f1.z); tmp[7] = f2bf(f1.w);
        } else {
            #pragma unroll
            for (int j = 0; j < 8; ++j)
                tmp[j] = (gk + j < DD) ? f2bf(x[(size_t)row * DD + gk + j]) : 0;
        }
    } else {
        #pragma unroll
        for (int j = 0; j < 8; ++j) tmp[j] = 0;
    }
    *((bf16x8*)&vbf[(size_t)row * KP + gk]) = *((bf16x8*)tmp);
}

// ---------------- CSR build ----------------
__global__ __launch_bounds__(256) void hist_deg(
    const int* __restrict__ src, const int* __restrict__ dst,
    int* __restrict__ deg)
{
    int e = blockIdx.x * 256 + threadIdx.x;
    if (e >= EE) return;
    atomicAdd(&deg[dst[e]], 1);
    atomicAdd(&deg[SCN + src[e]], 1);
}

__global__ __launch_bounds__(256) void scanA(
    const int* __restrict__ deg, int* __restrict__ off, int* __restrict__ bsum)
{
    __shared__ int ls[256];
    const int t = threadIdx.x, row = blockIdx.y;
    const int base = blockIdx.x * 2048 + t * 8;
    const int* dg = deg + (size_t)row * SCN + base;
    int v[8];
    #pragma unroll
    for (int j = 0; j < 8; ++j) v[j] = dg[j];
    int tot = 0;
    #pragma unroll
    for (int j = 0; j < 8; ++j) tot += v[j];
    ls[t] = tot;
    __syncthreads();
    #pragma unroll
    for (int d = 1; d < 256; d <<= 1) {
        int tv = (t >= d) ? ls[t - d] : 0;
        __syncthreads();
        ls[t] += tv;
        __syncthreads();
    }
    int run = ls[t] - tot;
    int* op = off + (size_t)row * SCN + base;
    #pragma unroll
    for (int j = 0; j < 8; ++j) { op[j] = run; run += v[j]; }
    if (t == 255) bsum[row * 64 + blockIdx.x] = ls[255];
}

__global__ __launch_bounds__(256) void scanB(int* __restrict__ bsum)
{
    if (threadIdx.x < 2) {
        int row = threadIdx.x, c = 0;
        for (int i = 0; i < NB; ++i) {
            int tv = bsum[row * 64 + i];
            bsum[row * 64 + i] = c;
            c += tv;
        }
    }
}

__global__ __launch_bounds__(256) void scanC(
    int* __restrict__ off, const int* __restrict__ bsum, int* __restrict__ cur)
{
    const int t = threadIdx.x, row = blockIdx.y;
    const int base = blockIdx.x * 2048 + t * 8;
    const int add = bsum[row * 64 + blockIdx.x];
    int* op = off + (size_t)row * SCN + base;
    int* cp = cur + (size_t)row * SCN + base;
    #pragma unroll
    for (int j = 0; j < 8; ++j) {
        int v = op[j] + add;
        op[j] = v;
        cp[j] = v;
    }
}

__global__ __launch_bounds__(256) void fill_adj(
    const int* __restrict__ src, const int* __restrict__ dst,
    int* __restrict__ cur, int* __restrict__ adj)
{
    int e = blockIdx.x * 256 + threadIdx.x;
    if (e >= EE) return;
    int s = src[e], d = dst[e];
    int pd = atomicAdd(&cur[d], 1);
    adj[pd] = s;
    int ps = atomicAdd(&cur[SCN + s], 1);
    adj[EE + ps] = d;
}

// ---------------- aggregation (no atomics, vectorized aligned gathers) ------
__global__ __launch_bounds__(256) void aggregate(
    const int* __restrict__ off, const int* __restrict__ adj,
    const unsigned short* __restrict__ P,
    const float* __restrict__ br, const float* __restrict__ bc,
    unsigned short* __restrict__ RC)
{
    const int n    = blockIdx.x * 4 + (threadIdx.x >> 6);
    const int dir  = blockIdx.y;
    const int lane = threadIdx.x & 63;
    const int c    = lane * 4;             // col base within 150-wide region

    if (lane < 10)
        RC[(size_t)n * KP + (dir ? 310 : 150) + lane] = 0;
    if (c >= 152) return;

    const int* offp = off + (size_t)dir * SCN;
    const int* adjp = adj + (size_t)dir * EE;
    const float* bias = dir ? bc : br;
    const unsigned short* own = P + (size_t)n * NPJ + (dir ? P_AC : P_AR);
    const int poff = dir ? P_BC : P_BR;
    const unsigned short* Pg = P + poff;

    const bool g0 = (c + 0) < 150, g1 = (c + 1) < 150;
    const bool g2 = (c + 2) < 150, g3 = (c + 3) < 150;

    bf16x4 ow = *((const bf16x4*)&own[c]);
    float o0 = bf2f((unsigned short)ow[0]) + (g0 ? bias[c + 0] : 0.f);
    float o1 = bf2f((unsigned short)ow[1]) + (g1 ? bias[c + 1] : 0.f);
    float o2 = bf2f((unsigned short)ow[2]) + (g2 ? bias[c + 2] : 0.f);
    float o3 = bf2f((unsigned short)ow[3]) + (g3 ? bias[c + 3] : 0.f);

    float s0 = 0.f, s1 = 0.f, s2 = 0.f, s3 = 0.f;
    int beg = offp[n], end = offp[n + 1];
    if (beg < end) {
        int a = adjp[beg];
        for (int i = beg; i < end; ++i) {
            int anext = (i + 1 < end) ? adjp[i + 1] : 0;
            const unsigned short* pp = Pg + (unsigned)a * (unsigned)NPJ;
            bf16x4 pv = *((const bf16x4*)&pp[c]);
            s0 += gelu_exact(o0 + bf2f((unsigned short)pv[0]));
            s1 += gelu_exact(o1 + bf2f((unsigned short)pv[1]));
            s2 += gelu_exact(o2 + bf2f((unsigned short)pv[2]));
            s3 += gelu_exact(o3 + bf2f((unsigned short)pv[3]));
            a = anext;
        }
    }
    unsigned short* outrow = RC + (size_t)n * KP + (dir ? RC_C : RC_R);
    if (c + 4 <= 150) {
        bf16x4 o;
        o[0] = (short)f2bf(s0); o[1] = (short)f2bf(s1);
        o[2] = (short)f2bf(s2); o[3] = (short)f2bf(s3);
        *((bf16x4*)&outrow[c]) = o;
    } else {
        if (g0) outrow[c + 0] = f2bf(s0);
        if (g1) outrow[c + 1] = f2bf(s1);
    }
}

// -------- low-LDS GEMM (R16, 20.5 KB LDS): tile 64x128, 4 waves --------------
#define GLOAD16(gp, lp) __builtin_amdgcn_global_load_lds( \
    (const __attribute__((address_space(1))) unsigned int*)(gp), \
    (__attribute__((address_space(3))) unsigned int*)(lp), 16, 0, 0)

// MODE 0: P[row*NPJ+col] = bf16(acc)
// MODE 1: nv = vbf_old + gelu(acc + bias[col]); last? out=fp32(nv) : vbf=bf16(nv)
template<int MODE>
__global__ __launch_bounds__(256) void gemm_lo(
    const unsigned short* __restrict__ Ab,
    const unsigned short* __restrict__ Bt,
    unsigned short* __restrict__ P,
    float* __restrict__ outv, unsigned short* __restrict__ vbf,
    const float* __restrict__ bias, int last)
{
    __shared__ unsigned short smem[10240];         // 20480 B total
    unsigned short* Alds = smem;                   // ring: 4 x 2048 shorts (16KB)

    const int tid  = threadIdx.x;
    const int lane = tid & 63;
    const int wid  = tid >> 6;

    // bijective XCD swizzle (m204)
    const int gx   = gridDim.x;
    const int nwg  = gx * gridDim.y;
    const int flat = blockIdx.y * gx + blockIdx.x;
    const int q = nwg >> 3, r = nwg & 7;
    const int xcd = flat & 7, off = flat >> 3;
    const int lid = (xcd < r ? xcd * (q + 1) : r * (q + 1) + (xcd - r) * q) + off;
    const int brow = (lid / gx) * 64;
    const int bcol = (lid % gx) * 128;
    const int wn   = wid * 32;

    f32x4 acc[4][2];
    #pragma unroll
    for (int i = 0; i < 4; ++i)
        #pragma unroll
        for (int j = 0; j < 2; ++j)
            #pragma unroll
            for (int rr = 0; rr < 4; ++rr) acc[i][j][rr] = 0.f;

    // ---- B panel fragments ----
    bf16x8 bfr[NTK][2];
    const unsigned short* Bb =
        Bt + (size_t)(bcol + wn + (lane & 15)) * KP + (lane >> 4) * 8;
    #pragma unroll
    for (int t = 0; t < NTK; ++t) {
        bfr[t][0] = *((const bf16x8*)(Bb + t * 32));
        bfr[t][1] = *((const bf16x8*)(Bb + (size_t)16 * KP + t * 32));
    }

    // per-thread A staging coords (chunk = tid; 64 rows x 4 chunks of 16B)
    const int arow = tid >> 2;
    const int ac   = (tid & 3) ^ ((arow >> 1) & 3);   // swizzled source chunk
    const unsigned short* asrc = Ab + (size_t)(brow + arow) * KP + ac * 8;

    // prologue: stage A tiles 0,1,2 (1 vmem op per wave per tile)
    #pragma unroll
    for (int t = 0; t < 3; ++t)
        GLOAD16(asrc + t * 32, Alds + t * 2048 + wid * 512);

    #pragma unroll
    for (int t = 0; t < NTK; ++t) {
        unsigned short* Alc = Alds + (t & 3) * 2048;
        if (t + 2 < NTK) {
            asm volatile("s_waitcnt vmcnt(2)" ::: "memory");
        } else if (t + 1 < NTK) {
            asm volatile("s_waitcnt vmcnt(1)" ::: "memory");
        } else {
            asm volatile("s_waitcnt vmcnt(0)" ::: "memory");
        }
        __builtin_amdgcn_s_barrier();
        if (t + 3 < NTK)
            GLOAD16(asrc + (t + 3) * 32, Alds + ((t + 3) & 3) * 2048 + wid * 512);

        bf16x8 af[4];
        #pragma unroll
        for (int mi = 0; mi < 4; ++mi) {
            int row = mi * 16 + (lane & 15);
            af[mi] = *((const bf16x8*)&Alc[row * 32 + (((lane >> 4) ^ ((row >> 1) & 3)) * 8)]);
        }
        __builtin_amdgcn_s_setprio(1);
        #pragma unroll
        for (int mi = 0; mi < 4; ++mi)
            #pragma unroll
            for (int nj = 0; nj < 2; ++nj)
                acc[mi][nj] = __builtin_amdgcn_mfma_f32_16x16x32_bf16(
                    af[mi], bfr[t][nj], acc[mi][nj], 0, 0, 0);
        __builtin_amdgcn_s_setprio(0);
    }
    __syncthreads();   // all waves done with A ring before per-wave bounce reuse

    if (MODE == 0) {
        // per-wave bf16 bounce [64][40] = 2560 shorts at smem + wid*2560
        unsigned short* sb = &smem[wid * 2560];
        #pragma unroll
        for (int mi = 0; mi < 4; ++mi)
            #pragma unroll
            for (int nj = 0; nj < 2; ++nj)
                #pragma unroll
                for (int rr = 0; rr < 4; ++rr) {
                    int row = mi * 16 + ((lane >> 4) << 2) + rr;
                    sb[row * 40 + nj * 16 + (lane & 15)] = f2bf(acc[mi][nj][rr]);
                }
        #pragma unroll
        for (int i = 0; i < 4; ++i) {
            int row = i * 16 + (lane >> 2);
            bf16x8 v = *((const bf16x8*)&sb[row * 40 + (lane & 3) * 8]);
            *((bf16x8*)&P[(size_t)(brow + row) * NPJ + bcol + wn + (lane & 3) * 8]) = v;
        }
    } else {
        // per-wave fp32 bounce [32][40] = 5120B, two 32-row passes
        float* fb = (float*)&smem[wid * 2560];
        const int gc = bcol + wn + (lane & 7) * 4;
        #pragma unroll
        for (int h = 0; h < 2; ++h) {
            #pragma unroll
            for (int mi2 = 0; mi2 < 2; ++mi2)
                #pragma unroll
                for (int nj = 0; nj < 2; ++nj)
                    #pragma unroll
                    for (int rr = 0; rr < 4; ++rr) {
                        int row32 = mi2 * 16 + ((lane >> 4) << 2) + rr;
                        fb[row32 * 40 + nj * 16 + (lane & 15)] = acc[h * 2 + mi2][nj][rr];
                    }
            #pragma unroll
            for (int i = 0; i < 4; ++i) {
                int row32 = i * 8 + (lane >> 3);
                int grow = brow + h * 32 + row32;
                float4 vv = *((const float4*)&fb[row32 * 40 + (lane & 7) * 4]);
                if (grow < NND) {
                    if (gc + 4 <= DD) {
                        float4 bv = *((const float4*)&bias[gc]);
                        bf16x4 old = *((const bf16x4*)&vbf[(size_t)grow * KP + gc]);
                        float4 nv;
                        nv.x = bf2f((unsigned short)old[0]) + gelu_exact(vv.x + bv.x);
                        nv.y = bf2f((unsigned short)old[1]) + gelu_exact(vv.y + bv.y);
                        nv.z = bf2f((unsigned short)old[2]) + gelu_exact(vv.z + bv.z);
                        nv.w = bf2f((unsigned short)old[3]) + gelu_exact(vv.w + bv.w);
                        if (last) {
                            *((float4*)&outv[(size_t)grow * DD + gc]) = nv;
                        } else {
                            bf16x4 o;
                            o[0] = (short)f2bf(nv.x); o[1] = (short)f2bf(nv.y);
                            o[2] = (short)f2bf(nv.z); o[3] = (short)f2bf(nv.w);
                            *((bf16x4*)&vbf[(size_t)grow * KP + gc]) = o;
                        }
                    } else {
                        #pragma unroll
                        for (int j = 0; j < 4; ++j) {
                            int ccc = gc + j;
                            if (ccc < DD) {
                                float vj = (j == 0) ? vv.x : (j == 1) ? vv.y
                                         : (j == 2) ? vv.z : vv.w;
                                size_t vidx = (size_t)grow * KP + ccc;
                                float nv = bf2f(vbf[vidx]) + gelu_exact(vj + bias[ccc]);
                                if (last) outv[(size_t)grow * DD + ccc] = nv;
                                else      vbf[vidx] = f2bf(nv);
                            }
                        }
                    }
                }
            }
        }
    }
}

extern "C" void kernel_launch(void* const* d_in, const int* in_sizes, int n_in,
                              void* d_out, int out_size, void* d_ws, size_t ws_size,
                              hipStream_t stream) {
    const float* x  = (const float*)d_in[0];
    const int*   ei = (const int*)  d_in[1];
    const float* Wr = (const float*)d_in[2];
    const float* br = (const float*)d_in[3];
    const float* Wc = (const float*)d_in[4];
    const float* bc = (const float*)d_in[5];
    const float* Wa = (const float*)d_in[6];
    const float* ba = (const float*)d_in[7];
    float* out = (float*)d_out;

    const size_t P_elems   = (size_t)MPAD * NPJ;   // bf16
    const size_t RC_elems  = (size_t)MPAD * KP;    // bf16
    const size_t V_elems   = (size_t)MPAD * KP;    // bf16
    const size_t Bt_elems  = (size_t)LL * NPJ * KP;
    const size_t Wat_elems = (size_t)NUP * KP;

    unsigned short* P   = (unsigned short*)d_ws;
    unsigned short* RC  = P + P_elems;
    unsigned short* vbf = RC + RC_elems;
    unsigned short* Bt  = vbf + V_elems;
    unsigned short* Wat = Bt + Bt_elems;
    int* deg  = (int*)(Wat + Wat_elems);
    int* off  = deg + 2 * SCN;
    int* curp = off + 2 * SCN;
    int* adj  = curp + 2 * SCN;
    int* bsum = adj + 2 * EE;
    const size_t need = (char*)(bsum + 128) - (char*)d_ws;
    if (ws_size < need) return;  // visible fail (output stays poisoned)

    pack_w<<<2880, 256, 0, stream>>>(Wr, Wc, Wa, Bt, Wat);
    init_vbf<<<(int)((V_elems / 8 + 255) / 256), 256, 0, stream>>>(x, vbf);

    const int* src = ei;
    const int* dst = ei + EE;

    hipMemsetAsync(deg, 0, 2 * SCN * sizeof(int), stream);
    hist_deg<<<(EE + 255) / 256, 256, 0, stream>>>(src, dst, deg);
    scanA<<<dim3(NB, 2), 256, 0, stream>>>(deg, off, bsum);
    scanB<<<1, 256, 0, stream>>>(bsum);
    scanC<<<dim3(NB, 2), 256, 0, stream>>>(off, bsum, curp);
    fill_adj<<<(EE + 255) / 256, 256, 0, stream>>>(src, dst, curp, adj);

    dim3 gproj(NPJ / 128, MPAD / 64);   // (5, 1564)
    dim3 gupd (NUP / 128, MPAD / 64);   // (3, 1564)
    dim3 gagg (MPAD / 4, 2);

    for (int l = 0; l < LL; ++l) {
        gemm_lo<0><<<gproj, 256, 0, stream>>>(
            vbf, Bt + (size_t)l * NPJ * KP, P, nullptr, nullptr, nullptr, 0);
        aggregate<<<gagg, 256, 0, stream>>>(
            off, adj, P, br + (size_t)l * HH, bc + (size_t)l * HH, RC);
        gemm_lo<1><<<gupd, 256, 0, stream>>>(
            RC, Wat, nullptr, out, vbf, ba, (l == LL - 1) ? 1 : 0);
    }
}